// Round 1
// baseline (1501.435 us; speedup 1.0000x reference)
//
#include <hip/hip_runtime.h>
#include <hip/hip_bf16.h>

#define N_NODES 200000
#define D 64

// ---------------- zero-init (graph-capture-safe, deterministic) ----------------
__global__ __launch_bounds__(256) void zero_kernel(float4* __restrict__ p, int n4) {
    int i = blockIdx.x * blockDim.x + threadIdx.x;
    if (i < n4) p[i] = make_float4(0.f, 0.f, 0.f, 0.f);
}

// ---------------- SpMM scatter: eout[r] += v * ein[c], one edge per wave ----------------
__global__ __launch_bounds__(256) void spmm_scatter(const int* __restrict__ rows,
                                                    const int* __restrict__ cols,
                                                    const float* __restrict__ vals,
                                                    const float* __restrict__ ein,
                                                    float* __restrict__ eout,
                                                    int E) {
    int gid  = blockIdx.x * blockDim.x + threadIdx.x;
    int wid  = gid >> 6;
    int lane = threadIdx.x & 63;
    int nw   = (gridDim.x * blockDim.x) >> 6;
    for (int e = wid; e < E; e += nw) {
        int   r = rows[e];
        int   c = cols[e];
        float v = vals[e];
        float x = ein[(size_t)c * D + lane];
#if defined(__HIP_DEVICE_COMPILE__)
        unsafeAtomicAdd(&eout[(size_t)r * D + lane], v * x);
#else
        atomicAdd(&eout[(size_t)r * D + lane], v * x);
#endif
    }
}

// ---------------- fused 2-layer residual MLP + LayerNorm, in-place ----------------
// y = relu(x @ W^T + b) + x   (x2), then LN over D with gamma/beta.
// One wave per row (lane = feature d). W in LDS padded [64][68] (stride 68 words
// == 4 mod 32 -> ds_read_b128 at the 8-phase floor, conflict-free).
__global__ __launch_bounds__(256) void mlp_ln_kernel(float* __restrict__ e,
                                                     const float* __restrict__ Ws,
                                                     const float* __restrict__ bs,
                                                     const float* __restrict__ gamma,
                                                     const float* __restrict__ beta) {
    __shared__ float W[2][D][68];
    __shared__ float bsh[2][D];
    __shared__ float gsh[D];
    __shared__ float bet[D];
    __shared__ float X[4][D];   // per-wave x broadcast buffer

    int t = threadIdx.x;
    for (int i = t; i < 2 * D * D; i += 256) {
        int l = i >> 12;           // 4096 per layer
        int r = (i >> 6) & 63;
        int c = i & 63;
        W[l][r][c] = Ws[i];
    }
    if (t < 128) bsh[t >> 6][t & 63] = bs[t];
    if (t < 64) { gsh[t] = gamma[t]; bet[t] = beta[t]; }
    __syncthreads();

    int wave = t >> 6;
    int lane = t & 63;
    int gwave  = blockIdx.x * 4 + wave;
    int nwaves = gridDim.x * 4;
    float* Xw = X[wave];

    for (int row = gwave; row < N_NODES; row += nwaves) {
        float x = e[(size_t)row * D + lane];
        #pragma unroll
        for (int l = 0; l < 2; ++l) {
            Xw[lane] = x;                       // within-wave LDS broadcast stage
            float acc = bsh[l][lane];
            #pragma unroll
            for (int k4 = 0; k4 < 16; ++k4) {
                float4 w  = *(const float4*)&W[l][lane][k4 * 4];
                float4 xv = *(const float4*)&Xw[k4 * 4];
                acc += w.x * xv.x + w.y * xv.y + w.z * xv.z + w.w * xv.w;
            }
            x = fmaxf(acc, 0.f) + x;            // relu + residual
        }
        // LayerNorm across the 64 lanes
        float s = x;
        #pragma unroll
        for (int off = 32; off; off >>= 1) s += __shfl_xor(s, off);
        float mu = s * (1.f / 64.f);
        float xc = x - mu;
        float v2 = xc * xc;
        #pragma unroll
        for (int off = 32; off; off >>= 1) v2 += __shfl_xor(v2, off);
        float var = v2 * (1.f / 64.f);
        e[(size_t)row * D + lane] = xc * rsqrtf(var + 1e-5f) * gsh[lane] + bet[lane];
    }
}

extern "C" void kernel_launch(void* const* d_in, const int* in_sizes, int n_in,
                              void* d_out, int out_size, void* d_ws, size_t ws_size,
                              hipStream_t stream) {
    const int*   rows  = (const int*)d_in[0];
    const int*   cols  = (const int*)d_in[1];
    const float* vals  = (const float*)d_in[2];
    const float* ini   = (const float*)d_in[3];
    const float* Ws    = (const float*)d_in[4];
    const float* bs    = (const float*)d_in[5];
    const float* gamma = (const float*)d_in[6];
    const float* beta  = (const float*)d_in[7];
    float* out = (float*)d_out;
    float* e1  = (float*)d_ws;          // needs N_NODES*D*4 = 51.2 MB
    int E = in_sizes[0];

    int n4 = out_size / 4;              // 12.8M floats -> 3.2M float4
    int zb = (n4 + 255) / 256;
    zero_kernel<<<zb, 256, 0, stream>>>((float4*)e1,  n4);
    zero_kernel<<<zb, 256, 0, stream>>>((float4*)out, n4);

    int spmm_blocks = 12800;            // 51200 waves, grid-stride over E edges
    spmm_scatter<<<spmm_blocks, 256, 0, stream>>>(rows, cols, vals, ini, e1, E);
    spmm_scatter<<<spmm_blocks, 256, 0, stream>>>(rows, cols, vals, e1, out, E);

    mlp_ln_kernel<<<2048, 256, 0, stream>>>(out, Ws, bs, gamma, beta);
}

// Round 2
// 751.872 us; speedup vs baseline: 1.9969x; 1.9969x over previous
//
#include <hip/hip_runtime.h>
#include <hip/hip_bf16.h>

#define NN 200000
#define D 64
#define SCAN_B 1024

// ---------------- utility zero kernels (graph-capture-safe) ----------------
__global__ __launch_bounds__(256) void zero_f4(float4* __restrict__ p, int n4) {
    int i = blockIdx.x * blockDim.x + threadIdx.x;
    if (i < n4) p[i] = make_float4(0.f, 0.f, 0.f, 0.f);
}
__global__ __launch_bounds__(256) void zero_i(int* __restrict__ p, int n) {
    int i = blockIdx.x * blockDim.x + threadIdx.x;
    if (i < n) p[i] = 0;
}

// ---------------- CSR build ----------------
__global__ __launch_bounds__(256) void count_rows(const int* __restrict__ rows,
                                                  int* __restrict__ cnt, int E) {
    int i = blockIdx.x * blockDim.x + threadIdx.x;
    if (i < E) atomicAdd(&cnt[rows[i]], 1);
}

// per-block inclusive scan of counts -> tmp, block totals -> totals
__global__ __launch_bounds__(SCAN_B) void scan1(const int* __restrict__ cnt,
                                                int* __restrict__ tmp,
                                                int* __restrict__ totals, int n) {
    __shared__ int s[SCAN_B];
    int t = threadIdx.x;
    int i = blockIdx.x * SCAN_B + t;
    int v = (i < n) ? cnt[i] : 0;
    s[t] = v;
    __syncthreads();
    #pragma unroll
    for (int off = 1; off < SCAN_B; off <<= 1) {
        int add = (t >= off) ? s[t - off] : 0;
        __syncthreads();
        s[t] += add;
        __syncthreads();
    }
    if (i < n) tmp[i] = s[t];
    if (t == SCAN_B - 1) totals[blockIdx.x] = s[t];
}

// single-block exclusive scan of block totals (nb <= 256); also row_ptr[N] = E
__global__ __launch_bounds__(256) void scan2(int* __restrict__ totals, int nb,
                                             int* __restrict__ row_ptr, int n, int E) {
    __shared__ int s[256];
    int t = threadIdx.x;
    int v = (t < nb) ? totals[t] : 0;
    s[t] = v;
    __syncthreads();
    #pragma unroll
    for (int off = 1; off < 256; off <<= 1) {
        int add = (t >= off) ? s[t - off] : 0;
        __syncthreads();
        s[t] += add;
        __syncthreads();
    }
    if (t < nb) totals[t] = s[t] - v;   // exclusive
    if (t == 0) row_ptr[n] = E;
}

// row_ptr[i] = exclusive prefix; also init cursor[i] (in-place over counts)
__global__ __launch_bounds__(SCAN_B) void scan3(const int* __restrict__ tmp,
                                                int* __restrict__ cnt_cursor,
                                                const int* __restrict__ totals,
                                                int* __restrict__ row_ptr, int n) {
    int i = blockIdx.x * SCAN_B + threadIdx.x;
    if (i >= n) return;
    int v = totals[blockIdx.x] + tmp[i] - cnt_cursor[i];
    row_ptr[i] = v;
    cnt_cursor[i] = v;
}

__global__ __launch_bounds__(256) void scatter_edges(const int* __restrict__ rows,
                                                     const int* __restrict__ cols,
                                                     const float* __restrict__ vals,
                                                     int* __restrict__ cursor,
                                                     int2* __restrict__ packed, int E) {
    int i = blockIdx.x * blockDim.x + threadIdx.x;
    if (i >= E) return;
    int r = rows[i];
    int pos = atomicAdd(&cursor[r], 1);
    packed[pos] = make_int2(cols[i], __float_as_int(vals[i]));
}

// ---------------- gather SpMM: one wave per row, lane = feature ----------------
__global__ __launch_bounds__(256) void spmm_csr(const int* __restrict__ row_ptr,
                                                const int2* __restrict__ packed,
                                                const float* __restrict__ ein,
                                                float* __restrict__ eout, int n) {
    int wid  = (blockIdx.x * 256 + threadIdx.x) >> 6;
    int lane = threadIdx.x & 63;
    if (wid >= n) return;
    int start = row_ptr[wid];
    int end   = row_ptr[wid + 1];
    float acc = 0.f;
    for (int base = start; base < end; base += 64) {
        int cnt = end - base; if (cnt > 64) cnt = 64;
        int2 ev = make_int2(0, 0);
        if (lane < cnt) ev = packed[base + lane];
        int j = 0;
        for (; j + 4 <= cnt; j += 4) {
            int   c0 = __shfl(ev.x, j),     c1 = __shfl(ev.x, j + 1);
            int   c2 = __shfl(ev.x, j + 2), c3 = __shfl(ev.x, j + 3);
            float v0 = __int_as_float(__shfl(ev.y, j));
            float v1 = __int_as_float(__shfl(ev.y, j + 1));
            float v2 = __int_as_float(__shfl(ev.y, j + 2));
            float v3 = __int_as_float(__shfl(ev.y, j + 3));
            float x0 = ein[c0 * D + lane];
            float x1 = ein[c1 * D + lane];
            float x2 = ein[c2 * D + lane];
            float x3 = ein[c3 * D + lane];
            acc += v0 * x0; acc += v1 * x1; acc += v2 * x2; acc += v3 * x3;
        }
        for (; j < cnt; ++j) {
            int   c = __shfl(ev.x, j);
            float v = __int_as_float(__shfl(ev.y, j));
            acc += v * ein[c * D + lane];
        }
    }
    eout[(size_t)wid * D + lane] = acc;
}

// ---------------- fallback scatter SpMM (round-0 path) ----------------
__global__ __launch_bounds__(256) void spmm_scatter(const int* __restrict__ rows,
                                                    const int* __restrict__ cols,
                                                    const float* __restrict__ vals,
                                                    const float* __restrict__ ein,
                                                    float* __restrict__ eout, int E) {
    int gid  = blockIdx.x * blockDim.x + threadIdx.x;
    int wid  = gid >> 6;
    int lane = threadIdx.x & 63;
    int nw   = (gridDim.x * blockDim.x) >> 6;
    for (int e = wid; e < E; e += nw) {
        int   r = rows[e];
        int   c = cols[e];
        float v = vals[e];
        float x = ein[(size_t)c * D + lane];
        unsafeAtomicAdd(&eout[(size_t)r * D + lane], v * x);
    }
}

// ---------------- fused 2-layer residual MLP + LayerNorm, in-place ----------------
__global__ __launch_bounds__(256) void mlp_ln_kernel(float* __restrict__ e,
                                                     const float* __restrict__ Ws,
                                                     const float* __restrict__ bs,
                                                     const float* __restrict__ gamma,
                                                     const float* __restrict__ beta) {
    __shared__ float W[2][D][68];
    __shared__ float bsh[2][D];
    __shared__ float gsh[D];
    __shared__ float bet[D];
    __shared__ float X[4][D];

    int t = threadIdx.x;
    for (int i = t; i < 2 * D * D; i += 256) {
        int l = i >> 12;
        int r = (i >> 6) & 63;
        int c = i & 63;
        W[l][r][c] = Ws[i];
    }
    if (t < 128) bsh[t >> 6][t & 63] = bs[t];
    if (t < 64) { gsh[t] = gamma[t]; bet[t] = beta[t]; }
    __syncthreads();

    int wave = t >> 6;
    int lane = t & 63;
    int gwave  = blockIdx.x * 4 + wave;
    int nwaves = gridDim.x * 4;
    float* Xw = X[wave];

    for (int row = gwave; row < NN; row += nwaves) {
        float x = e[(size_t)row * D + lane];
        #pragma unroll
        for (int l = 0; l < 2; ++l) {
            Xw[lane] = x;
            float acc = bsh[l][lane];
            #pragma unroll
            for (int k4 = 0; k4 < 16; ++k4) {
                float4 w  = *(const float4*)&W[l][lane][k4 * 4];
                float4 xv = *(const float4*)&Xw[k4 * 4];
                acc += w.x * xv.x + w.y * xv.y + w.z * xv.z + w.w * xv.w;
            }
            x = fmaxf(acc, 0.f) + x;
        }
        float s = x;
        #pragma unroll
        for (int off = 32; off; off >>= 1) s += __shfl_xor(s, off);
        float mu = s * (1.f / 64.f);
        float xc = x - mu;
        float v2 = xc * xc;
        #pragma unroll
        for (int off = 32; off; off >>= 1) v2 += __shfl_xor(v2, off);
        float var = v2 * (1.f / 64.f);
        e[(size_t)row * D + lane] = xc * rsqrtf(var + 1e-5f) * gsh[lane] + bet[lane];
    }
}

extern "C" void kernel_launch(void* const* d_in, const int* in_sizes, int n_in,
                              void* d_out, int out_size, void* d_ws, size_t ws_size,
                              hipStream_t stream) {
    const int*   rows  = (const int*)d_in[0];
    const int*   cols  = (const int*)d_in[1];
    const float* vals  = (const float*)d_in[2];
    const float* ini   = (const float*)d_in[3];
    const float* Ws    = (const float*)d_in[4];
    const float* bs    = (const float*)d_in[5];
    const float* gamma = (const float*)d_in[6];
    const float* beta  = (const float*)d_in[7];
    float* out = (float*)d_out;
    int E = in_sizes[0];

    // ---- workspace layout (bytes, 16B-aligned) ----
    size_t e1_b     = (size_t)NN * D * 4;          // 51,200,000
    size_t packed_b = (size_t)E * 8;               // 25,600,000
    size_t ptr_b    = ((size_t)(NN + 1) * 4 + 15) & ~(size_t)15;
    size_t cur_b    = ((size_t)NN * 4 + 15) & ~(size_t)15;
    size_t tmp_b    = cur_b;
    size_t tot_b    = 1024;
    size_t need     = e1_b + packed_b + ptr_b + cur_b + tmp_b + tot_b;

    if (ws_size >= need) {
        char* w = (char*)d_ws;
        float* e1      = (float*)w;                    w += e1_b;
        int2*  packed  = (int2*)w;                     w += packed_b;
        int*   row_ptr = (int*)w;                      w += ptr_b;
        int*   cursor  = (int*)w;                      w += cur_b;
        int*   tmp     = (int*)w;                      w += tmp_b;
        int*   totals  = (int*)w;

        int nb_scan = (NN + SCAN_B - 1) / SCAN_B;      // 196
        zero_i<<<(NN + 255) / 256, 256, 0, stream>>>(cursor, NN);
        count_rows<<<(E + 255) / 256, 256, 0, stream>>>(rows, cursor, E);
        scan1<<<nb_scan, SCAN_B, 0, stream>>>(cursor, tmp, totals, NN);
        scan2<<<1, 256, 0, stream>>>(totals, nb_scan, row_ptr, NN, E);
        scan3<<<nb_scan, SCAN_B, 0, stream>>>(tmp, cursor, totals, row_ptr, NN);
        scatter_edges<<<(E + 255) / 256, 256, 0, stream>>>(rows, cols, vals, cursor, packed, E);

        int spmm_blocks = (NN * 64 + 255) / 256;       // 1 wave per row
        spmm_csr<<<spmm_blocks, 256, 0, stream>>>(row_ptr, packed, ini, e1, NN);
        spmm_csr<<<spmm_blocks, 256, 0, stream>>>(row_ptr, packed, e1, out, NN);
    } else {
        // fallback: atomic scatter path (needs only e1)
        float* e1 = (float*)d_ws;
        int n4 = out_size / 4;
        int zb = (n4 + 255) / 256;
        zero_f4<<<zb, 256, 0, stream>>>((float4*)e1,  n4);
        zero_f4<<<zb, 256, 0, stream>>>((float4*)out, n4);
        spmm_scatter<<<12800, 256, 0, stream>>>(rows, cols, vals, ini, e1, E);
        spmm_scatter<<<12800, 256, 0, stream>>>(rows, cols, vals, e1, out, E);
    }

    mlp_ln_kernel<<<2048, 256, 0, stream>>>(out, Ws, bs, gamma, beta);
}